// Round 2
// baseline (581.934 us; speedup 1.0000x reference)
//
#include <hip/hip_runtime.h>
#include <stdint.h>

// Problem constants
#define Bb 8
#define Ss 2048
#define Dd 512
#define Hh 8
#define Ee 64
#define Oo 512
#define Ff 512   // H*E

typedef _Float16 half_t;
typedef __attribute__((ext_vector_type(8))) _Float16 f16x8;  // 8 fp16 (4 VGPRs)
typedef __attribute__((ext_vector_type(4))) float f32x4;     // MFMA acc
typedef __attribute__((ext_vector_type(4))) float f4;
typedef __attribute__((ext_vector_type(4))) half_t h16x4;

// ---------------- query f32 -> f16 ----------------
__global__ __launch_bounds__(256) void k_cvt_x(const float* __restrict__ x,
                                               half_t* __restrict__ xh) {
    size_t i = ((size_t)blockIdx.x * 256 + threadIdx.x) * 4;
    f4 v = *(const f4*)(x + i);
    h16x4 o;
    o[0] = (half_t)v[0]; o[1] = (half_t)v[1]; o[2] = (half_t)v[2]; o[3] = (half_t)v[3];
    *(h16x4*)(xh + i) = o;
}

// -------- weights: Wq/Wk/Wv [H,D,E] -> f16 [H,E,D]; Wo [F,O] -> f16 [O,F] --------
__global__ __launch_bounds__(256) void k_cvt_w(const float* __restrict__ Wq, const float* __restrict__ Wk,
                                               const float* __restrict__ Wv, const float* __restrict__ Wo,
                                               half_t* __restrict__ WqT, half_t* __restrict__ WkT,
                                               half_t* __restrict__ WvT, half_t* __restrict__ WoT) {
    int t = blockIdx.x * 256 + threadIdx.x;            // 0 .. H*D*E-1 (== F*O-1)
    int h = t / (Dd * Ee); int rem = t - h * (Dd * Ee);
    int d = rem / Ee;      int e = rem - d * Ee;
    int ti = (h * Ee + e) * Dd + d;
    WqT[ti] = (half_t)Wq[t];
    WkT[ti] = (half_t)Wk[t];
    WvT[ti] = (half_t)Wv[t];
    int f = t / Oo; int o = t - f * Oo;
    WoT[o * Ff + f] = (half_t)Wo[t];
}

// ---------------- fused QKV projection ----------------
// grid (S/64, B*H), 256 thr (4 waves x 16 rows). Per wave: 16x64 out, K=512.
__global__ __launch_bounds__(256) void k_qkv(const half_t* __restrict__ xh,
                                             const half_t* __restrict__ WqT,
                                             const half_t* __restrict__ WkT,
                                             const half_t* __restrict__ WvT,
                                             half_t* __restrict__ Q,
                                             half_t* __restrict__ K,
                                             half_t* __restrict__ V) {
    int st = blockIdx.x, bh = blockIdx.y;
    int b = bh >> 3, h = bh & 7;
    int wave = threadIdx.x >> 6, lane = threadIdx.x & 63;
    int ar = lane & 15, kg = lane >> 4;

    const half_t* xr  = xh + ((size_t)b * Ss + st * 64 + wave * 16 + ar) * Dd + kg * 8;
    const half_t* wqb = WqT + (size_t)h * Ee * Dd + (size_t)ar * Dd + kg * 8;
    const half_t* wkb = WkT + (size_t)h * Ee * Dd + (size_t)ar * Dd + kg * 8;
    const half_t* wvb = WvT + (size_t)h * Ee * Dd + (size_t)ar * Dd + kg * 8;

    f32x4 aq[4], ak[4], av[4];
#pragma unroll
    for (int i = 0; i < 4; ++i) { aq[i] = (f32x4){0,0,0,0}; ak[i] = (f32x4){0,0,0,0}; av[i] = (f32x4){0,0,0,0}; }

    for (int k0 = 0; k0 < Dd; k0 += 32) {
        f16x8 a = *(const f16x8*)(xr + k0);
#pragma unroll
        for (int sub = 0; sub < 4; ++sub) {
            f16x8 bq = *(const f16x8*)(wqb + (size_t)sub * 16 * Dd + k0);
            aq[sub] = __builtin_amdgcn_mfma_f32_16x16x32_f16(a, bq, aq[sub], 0, 0, 0);
            f16x8 bk = *(const f16x8*)(wkb + (size_t)sub * 16 * Dd + k0);
            ak[sub] = __builtin_amdgcn_mfma_f32_16x16x32_f16(a, bk, ak[sub], 0, 0, 0);
            f16x8 bv = *(const f16x8*)(wvb + (size_t)sub * 16 * Dd + k0);
            av[sub] = __builtin_amdgcn_mfma_f32_16x16x32_f16(a, bv, av[sub], 0, 0, 0);
        }
    }
    // C/D layout: col = lane&15, row = (lane>>4)*4 + r   [measured m89]
    size_t obase = ((size_t)bh * Ss + st * 64 + wave * 16) * Ee;
#pragma unroll
    for (int sub = 0; sub < 4; ++sub)
#pragma unroll
        for (int r = 0; r < 4; ++r) {
            size_t oi = obase + (size_t)(kg * 4 + r) * Ee + sub * 16 + ar;
            Q[oi] = (half_t)aq[sub][r];
            K[oi] = (half_t)ak[sub][r];
            V[oi] = (half_t)av[sub][r];
        }
}

// ---------------- flash-style causal attention ----------------
// grid (S/64, B*H), 256 thr. Per wave: 16 q-rows; KV tile = 64.
__global__ __launch_bounds__(256) void k_attn(const half_t* __restrict__ Q,
                                              const half_t* __restrict__ Kg,
                                              const half_t* __restrict__ Vg,
                                              half_t* __restrict__ ctx) {
    __shared__ __attribute__((aligned(16))) half_t Vt[64][80];      // V^T tile: Vt[e][k], +16-pad
    __shared__ __attribute__((aligned(16))) half_t Pl[4][16][80];   // per-wave P tile [q][k]

    int qt = blockIdx.x, bh = blockIdx.y;
    int wave = threadIdx.x >> 6, lane = threadIdx.x & 63;
    int ar = lane & 15, kg = lane >> 4;
    int q0 = qt * 64;

    const half_t* Qb = Q  + (size_t)bh * Ss * Ee;
    const half_t* Kb = Kg + (size_t)bh * Ss * Ee;
    const half_t* Vb = Vg + (size_t)bh * Ss * Ee;

    // Q A-frags in registers (row = lane&15, k = (lane>>4)*8 + i)
    f16x8 qf0 = *(const f16x8*)(Qb + (size_t)(q0 + wave * 16 + ar) * Ee + kg * 8);
    f16x8 qf1 = *(const f16x8*)(Qb + (size_t)(q0 + wave * 16 + ar) * Ee + 32 + kg * 8);

    f32x4 o[4]; float m[4], l[4];
#pragma unroll
    for (int i = 0; i < 4; ++i) { o[i] = (f32x4){0,0,0,0}; m[i] = -1e30f; l[i] = 0.f; }

    int vr = threadIdx.x >> 2;           // V staging: row 0..63
    int vc = (threadIdx.x & 3) * 16;     // col base

    for (int kt = 0; kt <= qt; ++kt) {
        int k0 = kt * 64;
        __syncthreads();  // previous tile's LDS reads done
        {   // stage V^T (coalesced global read, scattered LDS write)
            const half_t* vs = Vb + (size_t)(k0 + vr) * Ee + vc;
            f16x8 v0 = *(const f16x8*)vs;
            f16x8 v1 = *(const f16x8*)(vs + 8);
#pragma unroll
            for (int j = 0; j < 8; ++j) {
                Vt[vc + j][vr]     = v0[j];
                Vt[vc + 8 + j][vr] = v1[j];
            }
        }
        // scores S = Q K^T  (K B-frags straight from global; L2-resident)
        f32x4 s[4];
#pragma unroll
        for (int sub = 0; sub < 4; ++sub) {
            s[sub] = (f32x4){0,0,0,0};
            f16x8 kf0 = *(const f16x8*)(Kb + (size_t)(k0 + sub * 16 + ar) * Ee + kg * 8);
            s[sub] = __builtin_amdgcn_mfma_f32_16x16x32_f16(qf0, kf0, s[sub], 0, 0, 0);
            f16x8 kf1 = *(const f16x8*)(Kb + (size_t)(k0 + sub * 16 + ar) * Ee + 32 + kg * 8);
            s[sub] = __builtin_amdgcn_mfma_f32_16x16x32_f16(qf1, kf1, s[sub], 0, 0, 0);
        }
        if (kt == qt) {  // causal mask on the diagonal tile (k0 == q0)
#pragma unroll
            for (int sub = 0; sub < 4; ++sub)
#pragma unroll
                for (int r = 0; r < 4; ++r)
                    if (sub * 16 + ar > wave * 16 + kg * 4 + r) s[sub][r] = -1e30f;
        }
        // online softmax update (row = kg*4+r, col = ar; reduce over 16 lanes)
#pragma unroll
        for (int r = 0; r < 4; ++r) {
            float mt = fmaxf(fmaxf(s[0][r], s[1][r]), fmaxf(s[2][r], s[3][r]));
            mt = fmaxf(mt, __shfl_xor(mt, 1));
            mt = fmaxf(mt, __shfl_xor(mt, 2));
            mt = fmaxf(mt, __shfl_xor(mt, 4));
            mt = fmaxf(mt, __shfl_xor(mt, 8));
            float mn = fmaxf(m[r], mt);
            float sc = __expf(m[r] - mn);
            float rs = 0.f;
#pragma unroll
            for (int sub = 0; sub < 4; ++sub) {
                float p = __expf(s[sub][r] - mn);
                rs += p;
                Pl[wave][kg * 4 + r][sub * 16 + ar] = (half_t)p;
            }
            rs += __shfl_xor(rs, 1);
            rs += __shfl_xor(rs, 2);
            rs += __shfl_xor(rs, 4);
            rs += __shfl_xor(rs, 8);
            l[r] = l[r] * sc + rs;
            m[r] = mn;
            o[0][r] *= sc; o[1][r] *= sc; o[2][r] *= sc; o[3][r] *= sc;
        }
        __syncthreads();  // V staged + P visible (lgkmcnt drained)
        // PV: o += P[16x64] * V[64x64]
        f16x8 pf0 = *(const f16x8*)&Pl[wave][ar][kg * 8];
        f16x8 pf1 = *(const f16x8*)&Pl[wave][ar][32 + kg * 8];
#pragma unroll
        for (int sub = 0; sub < 4; ++sub) {
            f16x8 vf0 = *(const f16x8*)&Vt[sub * 16 + ar][kg * 8];
            o[sub] = __builtin_amdgcn_mfma_f32_16x16x32_f16(pf0, vf0, o[sub], 0, 0, 0);
            f16x8 vf1 = *(const f16x8*)&Vt[sub * 16 + ar][32 + kg * 8];
            o[sub] = __builtin_amdgcn_mfma_f32_16x16x32_f16(pf1, vf1, o[sub], 0, 0, 0);
        }
    }
    // epilogue: ctx[b, s, h*E + e] f16 (head-major concat)
    int b = bh >> 3, h = bh & 7;
#pragma unroll
    for (int sub = 0; sub < 4; ++sub)
#pragma unroll
        for (int r = 0; r < 4; ++r) {
            int row = q0 + wave * 16 + kg * 4 + r;
            ctx[((size_t)b * Ss + row) * Ff + h * Ee + sub * 16 + ar] = (half_t)(o[sub][r] / l[r]);
        }
}

// ---------------- output projection: ctx[16384,512] x WoT -> out f32 ----------------
// grid (M/64, O/64) = (256, 8)
__global__ __launch_bounds__(256) void k_proj(const half_t* __restrict__ ctx,
                                              const half_t* __restrict__ WoT,
                                              float* __restrict__ out) {
    int mt = blockIdx.x, ot = blockIdx.y;
    int wave = threadIdx.x >> 6, lane = threadIdx.x & 63;
    int ar = lane & 15, kg = lane >> 4;

    const half_t* arow = ctx + ((size_t)mt * 64 + wave * 16 + ar) * Ff + kg * 8;
    const half_t* brow = WoT + ((size_t)ot * 64 + ar) * Ff + kg * 8;

    f32x4 acc[4];
#pragma unroll
    for (int i = 0; i < 4; ++i) acc[i] = (f32x4){0,0,0,0};

    for (int k0 = 0; k0 < Ff; k0 += 32) {
        f16x8 a = *(const f16x8*)(arow + k0);
#pragma unroll
        for (int sub = 0; sub < 4; ++sub) {
            f16x8 b = *(const f16x8*)(brow + (size_t)sub * 16 * Ff + k0);
            acc[sub] = __builtin_amdgcn_mfma_f32_16x16x32_f16(a, b, acc[sub], 0, 0, 0);
        }
    }
#pragma unroll
    for (int sub = 0; sub < 4; ++sub)
#pragma unroll
        for (int r = 0; r < 4; ++r)
            out[((size_t)mt * 64 + wave * 16 + kg * 4 + r) * Oo + ot * 64 + sub * 16 + ar] = acc[sub][r];
}

extern "C" void kernel_launch(void* const* d_in, const int* in_sizes, int n_in,
                              void* d_out, int out_size, void* d_ws, size_t ws_size,
                              hipStream_t stream) {
    const float* x  = (const float*)d_in[0];
    const float* Wq = (const float*)d_in[1];
    const float* Wk = (const float*)d_in[2];
    const float* Wv = (const float*)d_in[3];
    const float* Wo = (const float*)d_in[4];
    float* out = (float*)d_out;

    // workspace layout (all f16, fully rewritten every call): ~86 MB
    char* ws = (char*)d_ws;
    size_t off = 0;
    half_t* xh  = (half_t*)(ws + off); off += (size_t)Bb * Ss * Dd * 2;   // 16 MB
    half_t* WqT = (half_t*)(ws + off); off += (size_t)Hh * Ee * Dd * 2;
    half_t* WkT = (half_t*)(ws + off); off += (size_t)Hh * Ee * Dd * 2;
    half_t* WvT = (half_t*)(ws + off); off += (size_t)Hh * Ee * Dd * 2;
    half_t* WoT = (half_t*)(ws + off); off += (size_t)Ff * Oo * 2;
    half_t* Qd  = (half_t*)(ws + off); off += (size_t)Bb * Hh * Ss * Ee * 2;
    half_t* Kd  = (half_t*)(ws + off); off += (size_t)Bb * Hh * Ss * Ee * 2;
    half_t* Vd  = (half_t*)(ws + off); off += (size_t)Bb * Hh * Ss * Ee * 2;
    half_t* ctx = (half_t*)(ws + off); off += (size_t)Bb * Ss * Ff * 2;

    k_cvt_x<<<8192, 256, 0, stream>>>(x, xh);
    k_cvt_w<<<1024, 256, 0, stream>>>(Wq, Wk, Wv, Wo, WqT, WkT, WvT, WoT);
    k_qkv<<<dim3(Ss / 64, Bb * Hh), 256, 0, stream>>>(xh, WqT, WkT, WvT, Qd, Kd, Vd);
    k_attn<<<dim3(Ss / 64, Bb * Hh), 256, 0, stream>>>(Qd, Kd, Vd, ctx);
    k_proj<<<dim3((Bb * Ss) / 64, Oo / 64), 256, 0, stream>>>(ctx, WoT, out);
}

// Round 3
// 528.038 us; speedup vs baseline: 1.1021x; 1.1021x over previous
//
#include <hip/hip_runtime.h>
#include <stdint.h>

// Problem constants
#define Bb 8
#define Ss 2048
#define Dd 512
#define Hh 8
#define Ee 64
#define Oo 512
#define Ff 512   // H*E

typedef _Float16 half_t;
typedef __attribute__((ext_vector_type(8))) _Float16 f16x8;  // 8 fp16 (4 VGPRs)
typedef __attribute__((ext_vector_type(4))) float f32x4;     // MFMA acc
typedef __attribute__((ext_vector_type(4))) float f4;
typedef __attribute__((ext_vector_type(4))) half_t h16x4;

__device__ __forceinline__ float exp2_fast(float x) {
    float r; asm("v_exp_f32 %0, %1" : "=v"(r) : "v"(x)); return r;  // HW 2^x
}

// ---------------- query f32 -> f16 ----------------
__global__ __launch_bounds__(256) void k_cvt_x(const float* __restrict__ x,
                                               half_t* __restrict__ xh) {
    size_t i = ((size_t)blockIdx.x * 256 + threadIdx.x) * 4;
    f4 v = *(const f4*)(x + i);
    h16x4 o;
    o[0] = (half_t)v[0]; o[1] = (half_t)v[1]; o[2] = (half_t)v[2]; o[3] = (half_t)v[3];
    *(h16x4*)(xh + i) = o;
}

// -------- weights: Wq/Wk/Wv [H,D,E] -> f16 [H,E,D]; Wo [F,O] -> f16 [O,F] --------
__global__ __launch_bounds__(256) void k_cvt_w(const float* __restrict__ Wq, const float* __restrict__ Wk,
                                               const float* __restrict__ Wv, const float* __restrict__ Wo,
                                               half_t* __restrict__ WqT, half_t* __restrict__ WkT,
                                               half_t* __restrict__ WvT, half_t* __restrict__ WoT) {
    int t = blockIdx.x * 256 + threadIdx.x;            // 0 .. H*D*E-1 (== F*O-1)
    int h = t / (Dd * Ee); int rem = t - h * (Dd * Ee);
    int d = rem / Ee;      int e = rem - d * Ee;
    int ti = (h * Ee + e) * Dd + d;
    WqT[ti] = (half_t)Wq[t];
    WkT[ti] = (half_t)Wk[t];
    WvT[ti] = (half_t)Wv[t];
    int f = t / Oo; int o = t - f * Oo;
    WoT[o * Ff + f] = (half_t)Wo[t];
}

// ---------------- fused QKV projection ----------------
// grid (S/64, B*H), 256 thr (4 waves x 16 rows). Per wave: 16x64 out, K=512.
// V is written TRANSPOSED: Vt[bh][e][s]  (so k_attn reads V^T B-frags from L2)
__global__ __launch_bounds__(256) void k_qkv(const half_t* __restrict__ xh,
                                             const half_t* __restrict__ WqT,
                                             const half_t* __restrict__ WkT,
                                             const half_t* __restrict__ WvT,
                                             half_t* __restrict__ Q,
                                             half_t* __restrict__ K,
                                             half_t* __restrict__ Vt) {
    int st = blockIdx.x, bh = blockIdx.y;
    int b = bh >> 3, h = bh & 7;
    int wave = threadIdx.x >> 6, lane = threadIdx.x & 63;
    int ar = lane & 15, kg = lane >> 4;

    const half_t* xr  = xh + ((size_t)b * Ss + st * 64 + wave * 16 + ar) * Dd + kg * 8;
    const half_t* wqb = WqT + (size_t)h * Ee * Dd + (size_t)ar * Dd + kg * 8;
    const half_t* wkb = WkT + (size_t)h * Ee * Dd + (size_t)ar * Dd + kg * 8;
    const half_t* wvb = WvT + (size_t)h * Ee * Dd + (size_t)ar * Dd + kg * 8;

    f32x4 aq[4], ak[4], av[4];
#pragma unroll
    for (int i = 0; i < 4; ++i) { aq[i] = (f32x4){0,0,0,0}; ak[i] = (f32x4){0,0,0,0}; av[i] = (f32x4){0,0,0,0}; }

    for (int k0 = 0; k0 < Dd; k0 += 32) {
        f16x8 a = *(const f16x8*)(xr + k0);
#pragma unroll
        for (int sub = 0; sub < 4; ++sub) {
            f16x8 bq = *(const f16x8*)(wqb + (size_t)sub * 16 * Dd + k0);
            aq[sub] = __builtin_amdgcn_mfma_f32_16x16x32_f16(a, bq, aq[sub], 0, 0, 0);
            f16x8 bk = *(const f16x8*)(wkb + (size_t)sub * 16 * Dd + k0);
            ak[sub] = __builtin_amdgcn_mfma_f32_16x16x32_f16(a, bk, ak[sub], 0, 0, 0);
            f16x8 bv = *(const f16x8*)(wvb + (size_t)sub * 16 * Dd + k0);
            av[sub] = __builtin_amdgcn_mfma_f32_16x16x32_f16(a, bv, av[sub], 0, 0, 0);
        }
    }
    // C/D layout: col = lane&15, row = (lane>>4)*4 + r   [measured m89]
    size_t obase = ((size_t)bh * Ss + st * 64 + wave * 16) * Ee;
#pragma unroll
    for (int sub = 0; sub < 4; ++sub)
#pragma unroll
        for (int r = 0; r < 4; ++r) {
            int s_loc = st * 64 + wave * 16 + kg * 4 + r;
            size_t oi = obase + (size_t)(kg * 4 + r) * Ee + sub * 16 + ar;
            Q[oi] = (half_t)aq[sub][r];
            K[oi] = (half_t)ak[sub][r];
            Vt[((size_t)bh * Ee + sub * 16 + ar) * Ss + s_loc] = (half_t)av[sub][r];
        }
}

// ---------------- flash-style causal attention (barrier-free) ----------------
// grid (16, B*H), 256 thr (4 independent waves, 16 q-rows each).
// Each block does the balanced pair of q-tiles (bx, 31-bx): 33 KV-tile iters.
// K and V^T fragments read straight from global (L2-resident); P via per-wave LDS.
__global__ __launch_bounds__(256) void k_attn(const half_t* __restrict__ Q,
                                              const half_t* __restrict__ Kg,
                                              const half_t* __restrict__ Vtg,
                                              half_t* __restrict__ ctx) {
    __shared__ __attribute__((aligned(16))) half_t Pl[4][16][72];   // per-wave P tile [q][k]

    int bx = blockIdx.x, bh = blockIdx.y;
    int wave = threadIdx.x >> 6, lane = threadIdx.x & 63;
    int ar = lane & 15, kg = lane >> 4;
    int b = bh >> 3, h = bh & 7;

    const half_t* Qb = Q   + (size_t)bh * Ss * Ee;
    const half_t* Kb = Kg  + (size_t)bh * Ss * Ee;
    const half_t* Vb = Vtg + (size_t)bh * Ee * Ss;

    for (int hv = 0; hv < 2; ++hv) {
        int qt = hv ? (31 - bx) : bx;
        int q0 = qt * 64;

        // Q A-frags, pre-scaled by log2(e) so softmax runs in exp2 domain
        const half_t* qp = Qb + (size_t)(q0 + wave * 16 + ar) * Ee + kg * 8;
        f16x8 qf0 = *(const f16x8*)qp;
        f16x8 qf1 = *(const f16x8*)(qp + 32);
        const half_t l2e = (half_t)1.44269504f;
#pragma unroll
        for (int j = 0; j < 8; ++j) { qf0[j] *= l2e; qf1[j] *= l2e; }

        f32x4 o[4]; float m[4], l[4];
#pragma unroll
        for (int i = 0; i < 4; ++i) { o[i] = (f32x4){0,0,0,0}; m[i] = -1e30f; l[i] = 0.f; }

        for (int kt = 0; kt <= qt; ++kt) {
            int k0 = kt * 64;
            // scores S = Q K^T (log2 units); K B-frags straight from global
            f32x4 s[4];
            __builtin_amdgcn_s_setprio(1);
#pragma unroll
            for (int sub = 0; sub < 4; ++sub) {
                s[sub] = (f32x4){0,0,0,0};
                const half_t* kp = Kb + (size_t)(k0 + sub * 16 + ar) * Ee + kg * 8;
                f16x8 kf0 = *(const f16x8*)kp;
                s[sub] = __builtin_amdgcn_mfma_f32_16x16x32_f16(qf0, kf0, s[sub], 0, 0, 0);
                f16x8 kf1 = *(const f16x8*)(kp + 32);
                s[sub] = __builtin_amdgcn_mfma_f32_16x16x32_f16(qf1, kf1, s[sub], 0, 0, 0);
            }
            __builtin_amdgcn_s_setprio(0);
            if (kt == qt) {  // causal mask on the diagonal tile (k0 == q0)
#pragma unroll
                for (int sub = 0; sub < 4; ++sub)
#pragma unroll
                    for (int r = 0; r < 4; ++r)
                        if (sub * 16 + ar > wave * 16 + kg * 4 + r) s[sub][r] = -1e30f;
            }
            // online softmax (row = kg*4+r, col = ar; reduce over 16 lanes)
#pragma unroll
            for (int r = 0; r < 4; ++r) {
                float mt = fmaxf(fmaxf(s[0][r], s[1][r]), fmaxf(s[2][r], s[3][r]));
                mt = fmaxf(mt, __shfl_xor(mt, 1));
                mt = fmaxf(mt, __shfl_xor(mt, 2));
                mt = fmaxf(mt, __shfl_xor(mt, 4));
                mt = fmaxf(mt, __shfl_xor(mt, 8));
                float mn = fmaxf(m[r], mt);
                float sc = exp2_fast(m[r] - mn);
                float rs = 0.f;
#pragma unroll
                for (int sub = 0; sub < 4; ++sub) {
                    float p = exp2_fast(s[sub][r] - mn);
                    rs += p;
                    Pl[wave][kg * 4 + r][sub * 16 + ar] = (half_t)p;
                }
                rs += __shfl_xor(rs, 1);
                rs += __shfl_xor(rs, 2);
                rs += __shfl_xor(rs, 4);
                rs += __shfl_xor(rs, 8);
                l[r] = l[r] * sc + rs;
                m[r] = mn;
                o[0][r] *= sc; o[1][r] *= sc; o[2][r] *= sc; o[3][r] *= sc;
            }
            // PV: o += P[16x64] * V[64x64]; V^T B-frags straight from global
            f16x8 pf0 = *(const f16x8*)&Pl[wave][ar][kg * 8];
            f16x8 pf1 = *(const f16x8*)&Pl[wave][ar][32 + kg * 8];
            __builtin_amdgcn_s_setprio(1);
#pragma unroll
            for (int sub = 0; sub < 4; ++sub) {
                const half_t* vp = Vb + (size_t)(sub * 16 + ar) * Ss + k0 + kg * 8;
                f16x8 vf0 = *(const f16x8*)vp;
                o[sub] = __builtin_amdgcn_mfma_f32_16x16x32_f16(pf0, vf0, o[sub], 0, 0, 0);
                f16x8 vf1 = *(const f16x8*)(vp + 32);
                o[sub] = __builtin_amdgcn_mfma_f32_16x16x32_f16(pf1, vf1, o[sub], 0, 0, 0);
            }
            __builtin_amdgcn_s_setprio(0);
        }
        // epilogue: ctx[b, s, h*E + e] f16 (head-major concat)
#pragma unroll
        for (int sub = 0; sub < 4; ++sub)
#pragma unroll
            for (int r = 0; r < 4; ++r) {
                int row = q0 + wave * 16 + kg * 4 + r;
                ctx[((size_t)b * Ss + row) * Ff + h * Ee + sub * 16 + ar] = (half_t)(o[sub][r] / l[r]);
            }
    }
}

// ---------------- output projection: ctx[16384,512] x WoT -> out f32 ----------------
// grid (M/64, O/64) = (256, 8)
__global__ __launch_bounds__(256) void k_proj(const half_t* __restrict__ ctx,
                                              const half_t* __restrict__ WoT,
                                              float* __restrict__ out) {
    int mt = blockIdx.x, ot = blockIdx.y;
    int wave = threadIdx.x >> 6, lane = threadIdx.x & 63;
    int ar = lane & 15, kg = lane >> 4;

    const half_t* arow = ctx + ((size_t)mt * 64 + wave * 16 + ar) * Ff + kg * 8;
    const half_t* brow = WoT + ((size_t)ot * 64 + ar) * Ff + kg * 8;

    f32x4 acc[4];
#pragma unroll
    for (int i = 0; i < 4; ++i) acc[i] = (f32x4){0,0,0,0};

    for (int k0 = 0; k0 < Ff; k0 += 32) {
        f16x8 a = *(const f16x8*)(arow + k0);
#pragma unroll
        for (int sub = 0; sub < 4; ++sub) {
            f16x8 b = *(const f16x8*)(brow + (size_t)sub * 16 * Ff + k0);
            acc[sub] = __builtin_amdgcn_mfma_f32_16x16x32_f16(a, b, acc[sub], 0, 0, 0);
        }
    }
#pragma unroll
    for (int sub = 0; sub < 4; ++sub)
#pragma unroll
        for (int r = 0; r < 4; ++r)
            out[((size_t)mt * 64 + wave * 16 + kg * 4 + r) * Oo + ot * 64 + sub * 16 + ar] = acc[sub][r];
}

extern "C" void kernel_launch(void* const* d_in, const int* in_sizes, int n_in,
                              void* d_out, int out_size, void* d_ws, size_t ws_size,
                              hipStream_t stream) {
    const float* x  = (const float*)d_in[0];
    const float* Wq = (const float*)d_in[1];
    const float* Wk = (const float*)d_in[2];
    const float* Wv = (const float*)d_in[3];
    const float* Wo = (const float*)d_in[4];
    float* out = (float*)d_out;

    // workspace layout (all f16, fully rewritten every call): ~86 MB
    char* ws = (char*)d_ws;
    size_t off = 0;
    half_t* xh  = (half_t*)(ws + off); off += (size_t)Bb * Ss * Dd * 2;   // 16 MB
    half_t* WqT = (half_t*)(ws + off); off += (size_t)Hh * Ee * Dd * 2;
    half_t* WkT = (half_t*)(ws + off); off += (size_t)Hh * Ee * Dd * 2;
    half_t* WvT = (half_t*)(ws + off); off += (size_t)Hh * Ee * Dd * 2;
    half_t* WoT = (half_t*)(ws + off); off += (size_t)Ff * Oo * 2;
    half_t* Qd  = (half_t*)(ws + off); off += (size_t)Bb * Hh * Ss * Ee * 2;
    half_t* Kd  = (half_t*)(ws + off); off += (size_t)Bb * Hh * Ss * Ee * 2;
    half_t* Vtd = (half_t*)(ws + off); off += (size_t)Bb * Hh * Ss * Ee * 2;  // transposed [bh][e][s]
    half_t* ctx = (half_t*)(ws + off); off += (size_t)Bb * Ss * Ff * 2;

    k_cvt_x<<<8192, 256, 0, stream>>>(x, xh);
    k_cvt_w<<<1024, 256, 0, stream>>>(Wq, Wk, Wv, Wo, WqT, WkT, WvT, WoT);
    k_qkv<<<dim3(Ss / 64, Bb * Hh), 256, 0, stream>>>(xh, WqT, WkT, WvT, Qd, Kd, Vtd);
    k_attn<<<dim3(16, Bb * Hh), 256, 0, stream>>>(Qd, Kd, Vtd, ctx);
    k_proj<<<dim3((Bb * Ss) / 64, Oo / 64), 256, 0, stream>>>(ctx, WoT, out);
}